// Round 6
// baseline (1449.465 us; speedup 1.0000x reference)
//
#include <hip/hip_runtime.h>
#include <hip/hip_bf16.h>
#include <stdint.h>

// Problem constants (fixed shapes)
#define E_ 8
#define H_ 2048
#define I_ 4096
#define T_ 1024
#define K_ 2
#define GS_ 128
#define NPAIR (T_ * K_)   // 2048
#define N1 (2 * I_)       // 8192 flat out-features for gemm1

typedef __attribute__((ext_vector_type(8))) short s16x8;   // 8 bf16
typedef __attribute__((ext_vector_type(4))) float f32x4;   // MFMA C/D

static __device__ __forceinline__ unsigned short f2bf(float f) {
    __hip_bfloat16 h = __float2bfloat16(f);
    return __builtin_bit_cast(unsigned short, h);
}
static __device__ __forceinline__ float bf2f(unsigned short u) {
    uint32_t v = ((uint32_t)u) << 16;
    return __builtin_bit_cast(float, v);
}
// pack two f32 -> bf16x2 (round-half-up via +0x8000)
static __device__ __forceinline__ uint32_t pk2(float lo16, float hi16) {
    uint32_t a = __builtin_bit_cast(uint32_t, lo16) + 0x8000u;
    uint32_t b = __builtin_bit_cast(uint32_t, hi16) + 0x8000u;
    return (a >> 16) | (b & 0xffff0000u);
}

// dequant 4 packed bytes (int4 of int32s, one byte per int) -> 8 bf16 B-frag
static __device__ __forceinline__ s16x8 dq_frag(int4 q, float sc, float zp) {
    uint32_t r[4];
    int qa[4] = {q.x, q.y, q.z, q.w};
#pragma unroll
    for (int j = 0; j < 4; j++) {
        uint32_t byte = (uint32_t)qa[j] & 0xffu;
        float fh = (float)(byte >> 4) * sc + zp;   // even k (high nibble)
        float fl = (float)(byte & 15u) * sc + zp;  // odd k  (low nibble)
        r[j] = pk2(fh, fl);
    }
    union { uint4 u; s16x8 s; } cv;
    cv.u = make_uint4(r[0], r[1], r[2], r[3]);
    return cv.s;
}

// ---------------- x -> bf16 pre-pass ----------------
__global__ void x2bf_kernel(const float* __restrict__ x, unsigned short* __restrict__ xb) {
    int i = (blockIdx.x * 256 + threadIdx.x) * 8;
    float4 a = *(const float4*)(x + i);
    float4 b = *(const float4*)(x + i + 4);
    unsigned short t[8];
    t[0] = f2bf(a.x); t[1] = f2bf(a.y); t[2] = f2bf(a.z); t[3] = f2bf(a.w);
    t[4] = f2bf(b.x); t[5] = f2bf(b.y); t[6] = f2bf(b.z); t[7] = f2bf(b.w);
    *(s16x8*)(xb + i) = *(s16x8*)t;
}

// ---------------- zero output ----------------
__global__ void zero_f4(float4* p, int n4) {
    int i = blockIdx.x * blockDim.x + threadIdx.x;
    if (i < n4) p[i] = make_float4(0.f, 0.f, 0.f, 0.f);
}

// ---------------- router ----------------
__global__ void router_kernel(const int* __restrict__ ridx,
                              const float* __restrict__ rw,
                              int* __restrict__ seg,
                              int* __restrict__ ptok,
                              float* __restrict__ pw)
{
    __shared__ int cnt[E_];
    __shared__ int cur[E_];
    int tid = threadIdx.x;
    if (tid < E_) cnt[tid] = 0;
    __syncthreads();
    for (int p = tid; p < NPAIR; p += blockDim.x)
        atomicAdd(&cnt[ridx[p]], 1);
    __syncthreads();
    if (tid == 0) {
        int s = 0;
        for (int e = 0; e < E_; e++) { seg[e] = s; cur[e] = s; s += cnt[e]; }
        seg[E_] = s;
    }
    __syncthreads();
    for (int p = tid; p < NPAIR; p += blockDim.x) {
        int e = ridx[p];
        int pos = atomicAdd(&cur[e], 1);
        ptok[pos] = p >> 1;     // K_ == 2
        pw[pos] = rw[p];
    }
}

// ---------------- GEMM1 (barrier-free, register-direct) ----------------
// wave tile: 64(m slots) x 64(n out-features), K-step 32, no LDS, no syncthreads
__global__ __launch_bounds__(256, 4) void gemm1_kernel(
    const unsigned short* __restrict__ xb,   // [T][H] bf16
    const int* __restrict__ gu_packed,       // [E][2I][H/2] (one byte per int32)
    const float* __restrict__ gu_scales,     // [E][2I][H/GS]
    const float* __restrict__ gu_zeros,
    const int* __restrict__ seg,
    const int* __restrict__ ptok,
    unsigned short* __restrict__ gu_out)     // [NPAIR][N1]
{
    const int e = blockIdx.z;
    const int seg0 = seg[e], seg1 = seg[e + 1];
    const int m0 = blockIdx.y * 64;
    if (seg0 + m0 >= seg1) return;
    const int tid = threadIdx.x;
    const int lane = tid & 63;
    const int wave = tid >> 6;
    const int n0 = blockIdx.x * 256 + wave * 64;   // 4 waves = 4 n-tiles
    const int quad = lane >> 4;
    const int l16 = lane & 15;

    // A-frag row offsets: lane l16 = m-row, quad = k-chunk of 8
    int xoff[4];
#pragma unroll
    for (int mi = 0; mi < 4; mi++) {
        int slot = seg0 + m0 + mi * 16 + l16;
        if (slot > NPAIR - 1) slot = NPAIR - 1;
        xoff[mi] = ptok[slot] * H_ + quad * 8;
    }
    // B-frag row offsets: lane l16 = n-row
    int woff[4], soff[4];
#pragma unroll
    for (int ni = 0; ni < 4; ni++) {
        int n = n0 + ni * 16 + l16;
        woff[ni] = (e * N1 + n) * (H_ / 2) + quad * 4;
        soff[ni] = (e * N1 + n) * (H_ / GS_);
    }

    f32x4 acc[4][4];
#pragma unroll
    for (int mi = 0; mi < 4; mi++)
#pragma unroll
        for (int ni = 0; ni < 4; ni++)
            acc[mi][ni] = (f32x4){0.f, 0.f, 0.f, 0.f};

    for (int g = 0; g < H_ / GS_; g++) {       // 16 groups
        float s[4], z[4];
#pragma unroll
        for (int ni = 0; ni < 4; ni++) {
            s[ni] = gu_scales[soff[ni] + g];
            z[ni] = gu_zeros[soff[ni] + g];
        }
#pragma unroll
        for (int kk = 0; kk < 4; kk++) {       // 4 K-steps of 32 per group
            const int k0 = g * GS_ + kk * 32;
            s16x8 af[4];
#pragma unroll
            for (int mi = 0; mi < 4; mi++)
                af[mi] = *(const s16x8*)(xb + xoff[mi] + k0);
#pragma unroll
            for (int ni = 0; ni < 4; ni++) {
                int4 q = *(const int4*)(gu_packed + woff[ni] + (k0 >> 1));
                s16x8 wf = dq_frag(q, s[ni], z[ni]);
#pragma unroll
                for (int mi = 0; mi < 4; mi++)
                    acc[mi][ni] = __builtin_amdgcn_mfma_f32_16x16x32_bf16(af[mi], wf, acc[mi][ni], 0, 0, 0);
            }
        }
    }

    // epilogue: C/D row = quad*4+r (m), col = l16 (n)
#pragma unroll
    for (int mi = 0; mi < 4; mi++) {
#pragma unroll
        for (int r = 0; r < 4; r++) {
            const int slot = seg0 + m0 + mi * 16 + quad * 4 + r;
            if (slot < seg1) {
#pragma unroll
                for (int ni = 0; ni < 4; ni++)
                    gu_out[(size_t)slot * N1 + n0 + ni * 16 + l16] = f2bf(acc[mi][ni][r]);
            }
        }
    }
}

// ---------------- gelu(gate)*up in place (h -> gate half of gu) ----------------
__global__ void gelu_mul_kernel(unsigned short* __restrict__ gu) {
    int idx = blockIdx.x * 256 + threadIdx.x;   // one per 8 h-elements
    int s = idx >> 9;                           // I_/8 = 512 vecs per slot
    int c = (idx & 511) * 8;
    unsigned short* row = gu + (size_t)s * N1;
    s16x8 g8 = *(const s16x8*)(row + c);
    s16x8 u8 = *(const s16x8*)(row + I_ + c);
    unsigned short t[8];
#pragma unroll
    for (int j = 0; j < 8; j++) {
        float gv = bf2f((unsigned short)g8[j]);
        float uv = bf2f((unsigned short)u8[j]);
        float th = tanhf(0.7978845608028654f * (gv + 0.044715f * gv * gv * gv));
        t[j] = f2bf(0.5f * gv * (1.0f + th) * uv);
    }
    *(s16x8*)(row + c) = *(s16x8*)t;
}

// ---------------- GEMM2 (barrier-free, register-direct, K-split x4) ----------------
__global__ __launch_bounds__(256, 4) void gemm2_kernel(
    const unsigned short* __restrict__ gu,     // h in gate half, row stride N1
    const int* __restrict__ dn_packed,         // [E][H][I/2] (one byte per int32)
    const float* __restrict__ dn_scales,       // [E][H][I/GS]
    const float* __restrict__ dn_zeros,
    const int* __restrict__ seg,
    const int* __restrict__ ptok,
    const float* __restrict__ pw,
    float* __restrict__ out)                   // [T][H]
{
    const int z = blockIdx.z;
    const int e = z >> 2;
    const int ks = z & 3;                      // K-split quarter
    const int seg0 = seg[e], seg1 = seg[e + 1];
    const int m0 = blockIdx.y * 64;
    if (seg0 + m0 >= seg1) return;
    const int tid = threadIdx.x;
    const int lane = tid & 63;
    const int wave = tid >> 6;
    const int n0 = blockIdx.x * 256 + wave * 64;   // H/256 = 8 blocks.x
    const int quad = lane >> 4;
    const int l16 = lane & 15;

    int aoff[4];
#pragma unroll
    for (int mi = 0; mi < 4; mi++) {
        int slot = seg0 + m0 + mi * 16 + l16;
        if (slot > NPAIR - 1) slot = NPAIR - 1;
        aoff[mi] = slot * N1 + quad * 8;
    }
    int woff[4], soff[4];
#pragma unroll
    for (int ni = 0; ni < 4; ni++) {
        int n = n0 + ni * 16 + l16;
        woff[ni] = (e * H_ + n) * (I_ / 2) + quad * 4;
        soff[ni] = (e * H_ + n) * (I_ / GS_);
    }

    f32x4 acc[4][4];
#pragma unroll
    for (int mi = 0; mi < 4; mi++)
#pragma unroll
        for (int ni = 0; ni < 4; ni++)
            acc[mi][ni] = (f32x4){0.f, 0.f, 0.f, 0.f};

    for (int g = ks * 8; g < ks * 8 + 8; g++) {    // 8 groups per split (I/GS=32 total)
        float s[4], z4[4];
#pragma unroll
        for (int ni = 0; ni < 4; ni++) {
            s[ni]  = dn_scales[soff[ni] + g];
            z4[ni] = dn_zeros[soff[ni] + g];
        }
#pragma unroll
        for (int kk = 0; kk < 4; kk++) {
            const int k0 = g * GS_ + kk * 32;
            s16x8 af[4];
#pragma unroll
            for (int mi = 0; mi < 4; mi++)
                af[mi] = *(const s16x8*)(gu + aoff[mi] + k0);
#pragma unroll
            for (int ni = 0; ni < 4; ni++) {
                int4 q = *(const int4*)(dn_packed + woff[ni] + (k0 >> 1));
                s16x8 wf = dq_frag(q, s[ni], z4[ni]);
#pragma unroll
                for (int mi = 0; mi < 4; mi++)
                    acc[mi][ni] = __builtin_amdgcn_mfma_f32_16x16x32_bf16(af[mi], wf, acc[mi][ni], 0, 0, 0);
            }
        }
    }

#pragma unroll
    for (int mi = 0; mi < 4; mi++) {
#pragma unroll
        for (int r = 0; r < 4; r++) {
            const int slot = seg0 + m0 + mi * 16 + quad * 4 + r;
            if (slot < seg1) {
                const int tok = ptok[slot];
                const float cf = pw[slot];
#pragma unroll
                for (int ni = 0; ni < 4; ni++)
                    atomicAdd(&out[(size_t)tok * H_ + n0 + ni * 16 + l16], cf * acc[mi][ni][r]);
            }
        }
    }
}

// ---------------- launch ----------------
extern "C" void kernel_launch(void* const* d_in, const int* in_sizes, int n_in,
                              void* d_out, int out_size, void* d_ws, size_t ws_size,
                              hipStream_t stream) {
    const float* x    = (const float*)d_in[0];
    const int*   gu_p = (const int*)d_in[1];     // uint8 in reference -> int32 on device
    const float* gu_s = (const float*)d_in[2];
    const float* gu_z = (const float*)d_in[3];
    const int*   dn_p = (const int*)d_in[4];
    const float* dn_s = (const float*)d_in[5];
    const float* dn_z = (const float*)d_in[6];
    const int*   ridx = (const int*)d_in[7];
    const float* rw   = (const float*)d_in[8];

    char* ws = (char*)d_ws;
    int*            seg   = (int*)ws;                               // 16 ints
    int*            ptok  = (int*)(ws + 256);                       // 2048 ints
    float*          pw    = (float*)(ws + 256 + NPAIR * 4);         // 2048 floats
    unsigned short* gu    = (unsigned short*)(ws + 32768);          // 2048 x 8192 bf16 = 32 MB
    unsigned short* xb    = (unsigned short*)(ws + 32768 + (size_t)NPAIR * N1 * 2);  // 4 MB

    float* out = (float*)d_out;

    x2bf_kernel<<<T_ * H_ / (256 * 8), 256, 0, stream>>>(x, xb);
    zero_f4<<<(T_ * H_ / 4 + 255) / 256, 256, 0, stream>>>((float4*)out, T_ * H_ / 4);
    router_kernel<<<1, 256, 0, stream>>>(ridx, rw, seg, ptok, pw);
    gemm1_kernel<<<dim3(N1 / 256, NPAIR / 64, E_), 256, 0, stream>>>(
        xb, gu_p, gu_s, gu_z, seg, ptok, gu);
    gelu_mul_kernel<<<NPAIR * (I_ / 8) / 256, 256, 0, stream>>>(gu);
    gemm2_kernel<<<dim3(H_ / 256, NPAIR / 64, E_ * 4), 256, 0, stream>>>(
        gu, dn_p, dn_s, dn_z, seg, ptok, pw, out);
}